// Round 6
// baseline (1145.247 us; speedup 1.0000x reference)
//
#include <hip/hip_runtime.h>
#include <math.h>

// ---------------------------------------------------------------------------
// RetentionBlock: LN1 -> QKVG proj -> retention scan -> Wo + residual ->
//                 LN2 -> FFN(gelu) + residual
// B=4, L=4096, D_MODEL=1024, H=16, DH=64. All global inputs f32.
// R6: (1) SOUND pipelined K-loop (R5 had prefetch-before-barrier race):
//       order = waitcnt vmcnt(4); s_barrier; THEN prefetch k+2; reads; mfma.
//       Stage written (k+2)%3 holds tile k-1, whose reads completed before
//       every wave's barrier k. Dummy-wrap tail keeps vmcnt uniform; final
//       vmcnt(0) drain before LDS dealloc (R5's 2nd bug).
//     (2) XCD-aware swizzle: round-robin xcd = lin&7 gets an 8x*(NB/8)y
//       rectangle (3 MB < 4 MB per-XCD L2), y-slab pinned per XCD across
//       windows -> B resident in L2, A served by L3.
// ---------------------------------------------------------------------------

#define D_MODEL 1024
#define LSEQ    4096
#define BATCH   4
#define NROWS   (BATCH * LSEQ)      // 16384
#define HEADS   16
#define DH      64
#define CHUNK   128
#define NCH     (LSEQ / CHUNK)      // 32

typedef short  short8  __attribute__((ext_vector_type(8)));
typedef short  short4v __attribute__((ext_vector_type(4)));
typedef float  float4v __attribute__((ext_vector_type(4)));

__device__ inline short f2bf(float f) {
    unsigned u = __float_as_uint(f);
    u += 0x7fffu + ((u >> 16) & 1u);   // round-to-nearest-even
    return (short)(u >> 16);
}
__device__ inline float bf2f(short s) {
    return __uint_as_float(((unsigned)(unsigned short)s) << 16);
}

// async global->LDS, 16 bytes per lane; dest = wave-uniform base + lane*16
__device__ inline void load_lds16(const short* g, short* l) {
    __builtin_amdgcn_global_load_lds(
        (const __attribute__((address_space(1))) void*)g,
        (__attribute__((address_space(3))) void*)l,
        16, 0, 0);
}

// ---------------------------------------------------------------------------
// Transpose f32 [R][C] -> bf16 [C][R]
// ---------------------------------------------------------------------------
__global__ __launch_bounds__(1024) void transpose_f32_bf16(
    const float* __restrict__ in, short* __restrict__ out, int R, int C)
{
    __shared__ float tile[32][33];
    int tx = threadIdx.x, ty = threadIdx.y;
    int r = blockIdx.y * 32 + ty;
    int c = blockIdx.x * 32 + tx;
    tile[ty][tx] = in[(size_t)r * C + c];
    __syncthreads();
    out[(size_t)(blockIdx.x * 32 + ty) * R + blockIdx.y * 32 + tx] =
        f2bf(tile[tx][ty]);
}

// concat bq|bk|bv|bg -> bias_qkvg[4096]
__global__ __launch_bounds__(256) void concat_bias(
    const float* __restrict__ bq, const float* __restrict__ bk,
    const float* __restrict__ bv, const float* __restrict__ bg,
    float* __restrict__ out)
{
    int i = blockIdx.x * 256 + threadIdx.x;
    const float* src = (i < 1024) ? bq : (i < 2048) ? bk : (i < 3072) ? bv : bg;
    out[i] = src[i & 1023];
}

// ---------------------------------------------------------------------------
// Row LayerNorm: f32 [row][1024] -> bf16 [row][1024]. 1 block / row.
// ---------------------------------------------------------------------------
__global__ __launch_bounds__(256) void ln_kernel(
    const float* __restrict__ x, const float* __restrict__ g,
    const float* __restrict__ b, short* __restrict__ y)
{
    int row = blockIdx.x;
    int tid = threadIdx.x;
    const float4* xr = (const float4*)(x + (size_t)row * D_MODEL);
    float4 v = xr[tid];
    float s  = v.x + v.y + v.z + v.w;
    float ss = v.x * v.x + v.y * v.y + v.z * v.z + v.w * v.w;
    #pragma unroll
    for (int off = 32; off > 0; off >>= 1) {
        s  += __shfl_down(s, off);
        ss += __shfl_down(ss, off);
    }
    __shared__ float sbuf[8];
    int wv = tid >> 6, ln = tid & 63;
    if (ln == 0) { sbuf[wv] = s; sbuf[4 + wv] = ss; }
    __syncthreads();
    float tot  = sbuf[0] + sbuf[1] + sbuf[2] + sbuf[3];
    float tot2 = sbuf[4] + sbuf[5] + sbuf[6] + sbuf[7];
    float mu  = tot * (1.0f / D_MODEL);
    float var = tot2 * (1.0f / D_MODEL) - mu * mu;
    float rs  = rsqrtf(var + 1e-5f);
    float4 gg = ((const float4*)g)[tid];
    float4 bb = ((const float4*)b)[tid];
    short4v o;
    o.x = f2bf((v.x - mu) * rs * gg.x + bb.x);
    o.y = f2bf((v.y - mu) * rs * gg.y + bb.y);
    o.z = f2bf((v.z - mu) * rs * gg.z + bb.z);
    o.w = f2bf((v.w - mu) * rs * gg.w + bb.w);
    ((short4v*)y)[(size_t)row * 256 + tid] = o;
}

// ---------------------------------------------------------------------------
// bf16 MFMA GEMM: C[M][N] = A[M][K](bf16) * BT[N][K](bf16)^T, fused epilogue.
// Block 256 = 4 waves; tile 128x128; wave owns 64x64 as 4x4 of 16x16x32 MFMA.
// Staging: global_load_lds width=16, 3-stage LDS pipeline, distance-2
// prefetch issued AFTER the barrier, "s_waitcnt vmcnt(4); s_barrier" per iter.
// LDS slot map (16B units): slot(row, q) = row*4 + (q ^ ((row>>1)&3)).
// Grid: XCD-aware swizzle (see kernel_launch comment).
// mode 0: out_bf16 = (col>=3072 ? sigmoid : id)(acc + bias)        [QKVG]
// mode 1: out_f32  = acc + bias + res   (res==outf in-place is OK) [x2 / final]
// mode 2: out_bf16 = gelu_exact(acc + bias)                        [FFN mid]
// ---------------------------------------------------------------------------
__global__ __launch_bounds__(256) void gemm_bf16(
    const short* __restrict__ A, const short* __restrict__ BT,
    const float* __restrict__ bias, const float* __restrict__ res,
    float* __restrict__ outf, short* __restrict__ outb,
    int M, int N, int K, int mode)
{
    __shared__ short As[3 * 4096];   // 3 stages x 8 KB, slot-swizzled
    __shared__ short Bs[3 * 4096];

    // ---- XCD-aware swizzle ----
    // lin ids round-robin over 8 XCDs. Window = 8 x-blocks * all NBY y-blocks.
    // XCD k (= lin&7 within window) gets rectangle: 8 x-values * ys y-values,
    // with its y-slab (by in [k*ys, k*ys+ys)) PINNED across windows ->
    // B slab (<=1 MB) stays L2-resident; A rows come from L3.
    {
    }
    const int MBX = gridDim.x, NBY = gridDim.y;
    const int lin = blockIdx.x + blockIdx.y * MBX;
    const int winsz = 8 * NBY;               // 256 or 64 (pow2)
    const int w = lin / winsz;
    const int r = lin - w * winsz;
    const int xcd = r & 7;
    const int t   = r >> 3;                  // [0, NBY)
    const int ys  = (NBY >= 8) ? (NBY >> 3) : 1;
    const int by  = xcd * ys + (t & (ys - 1));
    const int bx  = w * 8 + (t / ys);

    const int tid  = threadIdx.x;
    const int row0 = bx * 128;
    const int col0 = by * 128;
    const int lane = tid & 63;
    const int wave = tid >> 6;
    const int wm = (wave & 1) << 6;
    const int wn = (wave >> 1) << 6;
    const int lm = lane & 15;            // m / n index within 16-tile
    const int q  = lane >> 4;            // kgroup 0..3 of this lane's fragment

    float4v acc[4][4];
    #pragma unroll
    for (int i = 0; i < 4; i++)
        #pragma unroll
        for (int j = 0; j < 4; j++)
            acc[i][j] = (float4v)(0.0f);

    // ---- staging decode (constant per lane; only k0 varies) ----
    const int s0 = wave * 64 + lane;
    const int s1 = 256 + wave * 64 + lane;
    const int r0 = s0 >> 2, q0 = (s0 & 3) ^ ((r0 >> 1) & 3);
    const int r1 = s1 >> 2, q1 = (s1 & 3) ^ ((r1 >> 1) & 3);
    const short* gA0 = A  + (size_t)(row0 + r0) * K + q0 * 8;
    const short* gA1 = A  + (size_t)(row0 + r1) * K + q1 * 8;
    const short* gB0 = BT + (size_t)(col0 + r0) * K + q0 * 8;
    const short* gB1 = BT + (size_t)(col0 + r1) * K + q1 * 8;
    short* lA0 = As + s0 * 8;
    short* lA1 = As + s1 * 8;
    short* lB0 = Bs + s0 * 8;
    short* lB1 = Bs + s1 * 8;

    // fragment-read swizzle: row = 16*t + lm  ->  (row>>1)&3 == (lm>>1)&3
    const int swz = (lm >> 1) & 3;
    const int qs  = q ^ swz;             // swizzled kgroup slot for reads

    // prologue: tile 0 -> stage 0, tile 1 -> stage 1 (4 loads each)
    load_lds16(gA0, lA0);
    load_lds16(gA1, lA1);
    load_lds16(gB0, lB0);
    load_lds16(gB1, lB1);
    load_lds16(gA0 + 32, lA0 + 4096);
    load_lds16(gA1 + 32, lA1 + 4096);
    load_lds16(gB0 + 32, lB0 + 4096);
    load_lds16(gB1 + 32, lB1 + 4096);

    int cur = 0;                         // stage holding tile k
    for (int k0 = 0; k0 < K; k0 += 32) {
        // Wait for tile k's loads (exactly the 4 of tile k+1 stay in flight),
        // then sync. All waves past this barrier => tile k fully in LDS and
        // all reads of tile k-1 are complete.
        asm volatile("s_waitcnt vmcnt(4)\n\ts_barrier" ::: "memory");

        // prefetch tile k+2 into stage (cur+2)%3 (the one that held tile k-1,
        // safe now). Past K: wrap to tile 0 (dummy, never read) to keep the
        // in-flight count uniform.
        int kn = k0 + 64; if (kn >= K) kn -= K;
        int nx = cur + 2; if (nx >= 3) nx -= 3;
        const int nb = nx * 4096;
        load_lds16(gA0 + kn, lA0 + nb);
        load_lds16(gA1 + kn, lA1 + nb);
        load_lds16(gB0 + kn, lB0 + nb);
        load_lds16(gB1 + kn, lB1 + nb);

        const short* Ab = As + cur * 4096;
        const short* Bb = Bs + cur * 4096;

        short8 af[4], bfr[4];
        #pragma unroll
        for (int i = 0; i < 4; i++)
            af[i] = *(const short8*)&Ab[((wm + i * 16 + lm) * 4 + qs) * 8];
        #pragma unroll
        for (int j = 0; j < 4; j++)
            bfr[j] = *(const short8*)&Bb[((wn + j * 16 + lm) * 4 + qs) * 8];
        #pragma unroll
        for (int i = 0; i < 4; i++)
            #pragma unroll
            for (int j = 0; j < 4; j++)
                acc[i][j] = __builtin_amdgcn_mfma_f32_16x16x32_bf16(
                    af[i], bfr[j], acc[i][j], 0, 0, 0);

        cur = (cur + 1 == 3) ? 0 : cur + 1;
    }
    // drain outstanding (dummy) lds-DMA before this block's LDS can be
    // reassigned -- without this, late-landing writes corrupt another block.
    asm volatile("s_waitcnt vmcnt(0)" ::: "memory");

    const int r4 = (lane >> 4) << 2;     // C/D: row=(lane>>4)*4+reg, col=lane&15
    #pragma unroll
    for (int i = 0; i < 4; i++) {
        #pragma unroll
        for (int j = 0; j < 4; j++) {
            int colg = col0 + wn + j * 16 + lm;
            float bcol = bias[colg];
            #pragma unroll
            for (int r2 = 0; r2 < 4; r2++) {
                int rowg = row0 + wm + i * 16 + r4 + r2;
                size_t idx = (size_t)rowg * N + colg;
                float v = acc[i][j][r2] + bcol;
                if (mode == 0) {
                    if (colg >= 3072) v = 1.0f / (1.0f + expf(-v));
                    outb[idx] = f2bf(v);
                } else if (mode == 1) {
                    outf[idx] = v + res[idx];
                } else {
                    v = 0.5f * v * (1.0f + erff(v * 0.70710678118654752f));
                    outb[idx] = f2bf(v);
                }
            }
        }
    }
}

// ---------------------------------------------------------------------------
// Retention scan (chunk-parallel). qkvg bf16 [16384][4096]: q|k|v|g sections.
// channel c = b*1024 + h*64 + d  (4096 channels), chunks of 128 timesteps.
// ---------------------------------------------------------------------------
__global__ __launch_bounds__(256) void scan_pass1(
    const short* __restrict__ qkvg, const float* __restrict__ dlogit,
    float* __restrict__ carry)
{
    int j  = blockIdx.x >> 4;
    int c  = ((blockIdx.x & 15) << 8) + threadIdx.x;
    int b  = c >> 10;
    int col = c & 1023;
    float decay = 1.0f / (1.0f + expf(-dlogit[col >> 6]));
    size_t base = ((size_t)b * LSEQ + j * CHUNK) * 4096 + col;
    float s = 0.0f;
    for (int t = 0; t < CHUNK; ++t) {
        float kk = bf2f(qkvg[base + 1024]);
        float vv = bf2f(qkvg[base + 2048]);
        s = decay * s + kk * vv;
        base += 4096;
    }
    carry[j * 4096 + c] = s;
}

__global__ __launch_bounds__(256) void scan_combine(
    const float* __restrict__ carry, const float* __restrict__ dlogit,
    float* __restrict__ sinit)
{
    int c = blockIdx.x * 256 + threadIdx.x;
    float decay = 1.0f / (1.0f + expf(-dlogit[(c & 1023) >> 6]));
    float dp = powf(decay, (float)CHUNK);
    float s = 0.0f;
    for (int j = 0; j < NCH; ++j) {
        sinit[j * 4096 + c] = s;
        s = dp * s + carry[j * 4096 + c];
    }
}

__global__ __launch_bounds__(256) void scan_pass2(
    const short* __restrict__ qkvg, const float* __restrict__ dlogit,
    const float* __restrict__ sinit, short* __restrict__ att)
{
    int j  = blockIdx.x >> 4;
    int c  = ((blockIdx.x & 15) << 8) + threadIdx.x;
    int b  = c >> 10;
    int col = c & 1023;
    float decay = 1.0f / (1.0f + expf(-dlogit[col >> 6]));
    float s = sinit[j * 4096 + c];
    size_t base  = ((size_t)b * LSEQ + j * CHUNK) * 4096 + col;
    size_t obase = ((size_t)b * LSEQ + j * CHUNK) * 1024 + col;
    for (int t = 0; t < CHUNK; ++t) {
        float qq = bf2f(qkvg[base]);
        float kk = bf2f(qkvg[base + 1024]);
        float vv = bf2f(qkvg[base + 2048]);
        float gg = bf2f(qkvg[base + 3072]);
        s = decay * s + kk * vv;
        att[obase] = f2bf(gg * qq * s * 0.125f);   // scale = DH^-0.5
        base += 4096; obase += 1024;
    }
}

// ---------------------------------------------------------------------------
extern "C" void kernel_launch(void* const* d_in, const int* in_sizes, int n_in,
                              void* d_out, int out_size, void* d_ws, size_t ws_size,
                              hipStream_t stream)
{
    const float* x      = (const float*)d_in[0];
    const float* ln1_g  = (const float*)d_in[1];
    const float* ln1_b  = (const float*)d_in[2];
    const float* Wq     = (const float*)d_in[3];
    const float* bq     = (const float*)d_in[4];
    const float* Wk     = (const float*)d_in[5];
    const float* bk     = (const float*)d_in[6];
    const float* Wv     = (const float*)d_in[7];
    const float* bv     = (const float*)d_in[8];
    const float* Wg     = (const float*)d_in[9];
    const float* bg     = (const float*)d_in[10];
    const float* dlog   = (const float*)d_in[11];
    const float* Wo     = (const float*)d_in[12];
    const float* bo     = (const float*)d_in[13];
    const float* ln2_g  = (const float*)d_in[14];
    const float* ln2_b  = (const float*)d_in[15];
    const float* W1     = (const float*)d_in[16];
    const float* b1     = (const float*)d_in[17];
    const float* W2     = (const float*)d_in[18];
    const float* b2     = (const float*)d_in[19];
    float* out = (float*)d_out;

    char* ws = (char*)d_ws;
    size_t off = 0;
    auto alloc = [&](size_t bytes) -> void* {
        void* p = ws + off;
        off += (bytes + 255) & ~(size_t)255;
        return p;
    };
    // ---- workspace layout (~196 MB total) ----
    short* WqkvgT = (short*)alloc((size_t)4096 * 1024 * 2);   // 8 MB  [n=4096][k=1024]
    short* WoT    = (short*)alloc((size_t)1024 * 1024 * 2);   // 2 MB  [n=1024][k=1024]
    short* W1T    = (short*)alloc((size_t)4096 * 1024 * 2);   // 8 MB  [n=4096][k=1024]
    short* W2T    = (short*)alloc((size_t)1024 * 4096 * 2);   // 8 MB  [n=1024][k=4096]
    float* biasq  = (float*)alloc((size_t)4096 * 4);
    float* carry  = (float*)alloc((size_t)NCH * 4096 * 4);    // 0.5 MB
    float* sinit  = (float*)alloc((size_t)NCH * 4096 * 4);    // 0.5 MB
    short* bufA   = (short*)alloc((size_t)NROWS * 1024 * 2);  // 32 MB: y -> att -> h
    short* bufB   = (short*)alloc((size_t)NROWS * 4096 * 2);  // 128 MB: qkvg -> ff1
    // x2 lives in d_out (64 MB saved); final GEMM does in-place residual.
    float* x2 = out;
    short* ybuf = bufA;   // LN1 output
    short* att  = bufA;   // scan output (ybuf dead by then)
    short* hbuf = bufA;   // LN2 output (att dead by then)
    short* qkvg = bufB;
    short* ff1  = bufB;   // qkvg dead after scan_pass2
    (void)in_sizes; (void)n_in; (void)out_size;

    if (off > ws_size) return;  // ws too small: fail validation cleanly, not a segfault

    dim3 tb(32, 32);
    // weight prep: transpose + bf16 cast (must rerun every call; ws is poisoned)
    transpose_f32_bf16<<<dim3(32, 32), tb, 0, stream>>>(Wq, WqkvgT + 0 * 1024 * 1024, 1024, 1024);
    transpose_f32_bf16<<<dim3(32, 32), tb, 0, stream>>>(Wk, WqkvgT + 1 * 1024 * 1024, 1024, 1024);
    transpose_f32_bf16<<<dim3(32, 32), tb, 0, stream>>>(Wv, WqkvgT + 2 * 1024 * 1024, 1024, 1024);
    transpose_f32_bf16<<<dim3(32, 32), tb, 0, stream>>>(Wg, WqkvgT + 3 * 1024 * 1024, 1024, 1024);
    transpose_f32_bf16<<<dim3(32, 32), tb, 0, stream>>>(Wo, WoT, 1024, 1024);
    transpose_f32_bf16<<<dim3(128, 32), tb, 0, stream>>>(W1, W1T, 1024, 4096);
    transpose_f32_bf16<<<dim3(32, 128), tb, 0, stream>>>(W2, W2T, 4096, 1024);
    concat_bias<<<16, 256, 0, stream>>>(bq, bk, bv, bg, biasq);

    // LN1: x -> y(bf16)
    ln_kernel<<<NROWS, 256, 0, stream>>>(x, ln1_g, ln1_b, ybuf);

    // QKVG projection (fused bias + sigmoid on G)
    gemm_bf16<<<dim3(128, 32), 256, 0, stream>>>(
        ybuf, WqkvgT, biasq, nullptr, nullptr, qkvg, NROWS, 4096, 1024, 0);

    // retention scan
    scan_pass1 <<<NCH * 16, 256, 0, stream>>>(qkvg, dlog, carry);
    scan_combine<<<16, 256, 0, stream>>>(carry, dlog, sinit);
    scan_pass2 <<<NCH * 16, 256, 0, stream>>>(qkvg, dlog, sinit, att);

    // output projection + residual: x2 = x + att@Wo + bo   (x2 == d_out)
    gemm_bf16<<<dim3(128, 8), 256, 0, stream>>>(
        att, WoT, bo, x, x2, nullptr, NROWS, 1024, 1024, 1);

    // LN2: x2 -> h(bf16)
    ln_kernel<<<NROWS, 256, 0, stream>>>(x2, ln2_g, ln2_b, hbuf);

    // FFN: ff1 = gelu(h@W1 + b1)  (bf16)
    gemm_bf16<<<dim3(128, 32), 256, 0, stream>>>(
        hbuf, W1T, b1, nullptr, nullptr, ff1, NROWS, 4096, 1024, 2);

    // out = x2 + ff1@W2 + b2   (in-place residual on d_out)
    gemm_bf16<<<dim3(128, 8), 256, 0, stream>>>(
        ff1, W2T, b2, x2, out, nullptr, NROWS, 1024, 4096, 1);
}

// Round 7
// 1108.172 us; speedup vs baseline: 1.0335x; 1.0335x over previous
//
#include <hip/hip_runtime.h>
#include <math.h>

// ---------------------------------------------------------------------------
// RetentionBlock: LN1 -> QKVG proj -> retention scan -> Wo + residual ->
//                 LN2 -> FFN(gelu) + residual
// B=4, L=4096, D_MODEL=1024, H=16, DH=64. All global inputs f32.
// R7: isolate R6's (sound) pipelined K-loop from R6's (bad) XCD swizzle.
//     - K-loop: 3-stage LDS, distance-2 prefetch AFTER the barrier,
//       "s_waitcnt vmcnt(4); s_barrier" per iter, final vmcnt(0) drain.
//     - Grid mapping: back to R4's measured-best simple window
//       (8 x-blocks per window, y fastest) -- FETCH was 225 MB there vs
//       598 MB with the XCD-pinned mapping (R6 post-mortem).
// ---------------------------------------------------------------------------

#define D_MODEL 1024
#define LSEQ    4096
#define BATCH   4
#define NROWS   (BATCH * LSEQ)      // 16384
#define HEADS   16
#define DH      64
#define CHUNK   128
#define NCH     (LSEQ / CHUNK)      // 32

typedef short  short8  __attribute__((ext_vector_type(8)));
typedef short  short4v __attribute__((ext_vector_type(4)));
typedef float  float4v __attribute__((ext_vector_type(4)));

__device__ inline short f2bf(float f) {
    unsigned u = __float_as_uint(f);
    u += 0x7fffu + ((u >> 16) & 1u);   // round-to-nearest-even
    return (short)(u >> 16);
}
__device__ inline float bf2f(short s) {
    return __uint_as_float(((unsigned)(unsigned short)s) << 16);
}

// async global->LDS, 16 bytes per lane; dest = wave-uniform base + lane*16
__device__ inline void load_lds16(const short* g, short* l) {
    __builtin_amdgcn_global_load_lds(
        (const __attribute__((address_space(1))) void*)g,
        (__attribute__((address_space(3))) void*)l,
        16, 0, 0);
}

// ---------------------------------------------------------------------------
// Transpose f32 [R][C] -> bf16 [C][R]
// ---------------------------------------------------------------------------
__global__ __launch_bounds__(1024) void transpose_f32_bf16(
    const float* __restrict__ in, short* __restrict__ out, int R, int C)
{
    __shared__ float tile[32][33];
    int tx = threadIdx.x, ty = threadIdx.y;
    int r = blockIdx.y * 32 + ty;
    int c = blockIdx.x * 32 + tx;
    tile[ty][tx] = in[(size_t)r * C + c];
    __syncthreads();
    out[(size_t)(blockIdx.x * 32 + ty) * R + blockIdx.y * 32 + tx] =
        f2bf(tile[tx][ty]);
}

// concat bq|bk|bv|bg -> bias_qkvg[4096]
__global__ __launch_bounds__(256) void concat_bias(
    const float* __restrict__ bq, const float* __restrict__ bk,
    const float* __restrict__ bv, const float* __restrict__ bg,
    float* __restrict__ out)
{
    int i = blockIdx.x * 256 + threadIdx.x;
    const float* src = (i < 1024) ? bq : (i < 2048) ? bk : (i < 3072) ? bv : bg;
    out[i] = src[i & 1023];
}

// ---------------------------------------------------------------------------
// Row LayerNorm: f32 [row][1024] -> bf16 [row][1024]. 1 block / row.
// ---------------------------------------------------------------------------
__global__ __launch_bounds__(256) void ln_kernel(
    const float* __restrict__ x, const float* __restrict__ g,
    const float* __restrict__ b, short* __restrict__ y)
{
    int row = blockIdx.x;
    int tid = threadIdx.x;
    const float4* xr = (const float4*)(x + (size_t)row * D_MODEL);
    float4 v = xr[tid];
    float s  = v.x + v.y + v.z + v.w;
    float ss = v.x * v.x + v.y * v.y + v.z * v.z + v.w * v.w;
    #pragma unroll
    for (int off = 32; off > 0; off >>= 1) {
        s  += __shfl_down(s, off);
        ss += __shfl_down(ss, off);
    }
    __shared__ float sbuf[8];
    int wv = tid >> 6, ln = tid & 63;
    if (ln == 0) { sbuf[wv] = s; sbuf[4 + wv] = ss; }
    __syncthreads();
    float tot  = sbuf[0] + sbuf[1] + sbuf[2] + sbuf[3];
    float tot2 = sbuf[4] + sbuf[5] + sbuf[6] + sbuf[7];
    float mu  = tot * (1.0f / D_MODEL);
    float var = tot2 * (1.0f / D_MODEL) - mu * mu;
    float rs  = rsqrtf(var + 1e-5f);
    float4 gg = ((const float4*)g)[tid];
    float4 bb = ((const float4*)b)[tid];
    short4v o;
    o.x = f2bf((v.x - mu) * rs * gg.x + bb.x);
    o.y = f2bf((v.y - mu) * rs * gg.y + bb.y);
    o.z = f2bf((v.z - mu) * rs * gg.z + bb.z);
    o.w = f2bf((v.w - mu) * rs * gg.w + bb.w);
    ((short4v*)y)[(size_t)row * 256 + tid] = o;
}

// ---------------------------------------------------------------------------
// bf16 MFMA GEMM: C[M][N] = A[M][K](bf16) * BT[N][K](bf16)^T, fused epilogue.
// Block 256 = 4 waves; tile 128x128; wave owns 64x64 as 4x4 of 16x16x32 MFMA.
// Staging: global_load_lds width=16, 3-stage LDS pipeline, distance-2
// prefetch issued AFTER the barrier, "s_waitcnt vmcnt(4); s_barrier" per iter.
// LDS slot map (16B units): slot(row, q) = row*4 + (q ^ ((row>>1)&3)).
// Grid swizzle: windows of 8 x-blocks, y fastest (R4 measured-best).
// mode 0: out_bf16 = (col>=3072 ? sigmoid : id)(acc + bias)        [QKVG]
// mode 1: out_f32  = acc + bias + res   (res==outf in-place is OK) [x2 / final]
// mode 2: out_bf16 = gelu_exact(acc + bias)                        [FFN mid]
// ---------------------------------------------------------------------------
__global__ __launch_bounds__(256) void gemm_bf16(
    const short* __restrict__ A, const short* __restrict__ BT,
    const float* __restrict__ bias, const float* __restrict__ res,
    float* __restrict__ outf, short* __restrict__ outb,
    int M, int N, int K, int mode)
{
    __shared__ short As[3 * 4096];   // 3 stages x 8 KB, slot-swizzled
    __shared__ short Bs[3 * 4096];

    // ---- grid swizzle: window = 8 x-values * all y, y fastest inside ----
    const int gx = gridDim.x, gy = gridDim.y;
    const int lin = blockIdx.x + blockIdx.y * gx;
    const int win = 8 * gy;
    const int grp = lin / win;
    const int rem = lin - grp * win;
    const int bx = grp * 8 + (rem & 7);
    const int by = rem >> 3;

    const int tid  = threadIdx.x;
    const int row0 = bx * 128;
    const int col0 = by * 128;
    const int lane = tid & 63;
    const int wave = tid >> 6;
    const int wm = (wave & 1) << 6;
    const int wn = (wave >> 1) << 6;
    const int lm = lane & 15;            // m / n index within 16-tile
    const int q  = lane >> 4;            // kgroup 0..3 of this lane's fragment

    float4v acc[4][4];
    #pragma unroll
    for (int i = 0; i < 4; i++)
        #pragma unroll
        for (int j = 0; j < 4; j++)
            acc[i][j] = (float4v)(0.0f);

    // ---- staging decode (constant per lane; only k0 varies) ----
    const int s0 = wave * 64 + lane;
    const int s1 = 256 + wave * 64 + lane;
    const int r0 = s0 >> 2, q0 = (s0 & 3) ^ ((r0 >> 1) & 3);
    const int r1 = s1 >> 2, q1 = (s1 & 3) ^ ((r1 >> 1) & 3);
    const short* gA0 = A  + (size_t)(row0 + r0) * K + q0 * 8;
    const short* gA1 = A  + (size_t)(row0 + r1) * K + q1 * 8;
    const short* gB0 = BT + (size_t)(col0 + r0) * K + q0 * 8;
    const short* gB1 = BT + (size_t)(col0 + r1) * K + q1 * 8;
    short* lA0 = As + s0 * 8;
    short* lA1 = As + s1 * 8;
    short* lB0 = Bs + s0 * 8;
    short* lB1 = Bs + s1 * 8;

    // fragment-read swizzle: row = 16*t + lm  ->  (row>>1)&3 == (lm>>1)&3
    const int swz = (lm >> 1) & 3;
    const int qs  = q ^ swz;             // swizzled kgroup slot for reads

    // prologue: tile 0 -> stage 0, tile 1 -> stage 1 (4 loads each)
    load_lds16(gA0, lA0);
    load_lds16(gA1, lA1);
    load_lds16(gB0, lB0);
    load_lds16(gB1, lB1);
    load_lds16(gA0 + 32, lA0 + 4096);
    load_lds16(gA1 + 32, lA1 + 4096);
    load_lds16(gB0 + 32, lB0 + 4096);
    load_lds16(gB1 + 32, lB1 + 4096);

    int cur = 0;                         // stage holding tile k
    for (int k0 = 0; k0 < K; k0 += 32) {
        // Wait for tile k's loads (exactly the 4 of tile k+1 stay in flight),
        // then sync. All waves past this barrier => tile k fully in LDS and
        // all reads of tile k-1 are complete.
        asm volatile("s_waitcnt vmcnt(4)\n\ts_barrier" ::: "memory");

        // prefetch tile k+2 into stage (cur+2)%3 (the one that held tile k-1,
        // safe now). Past K: wrap to tile 0 (dummy, never read) to keep the
        // in-flight count uniform.
        int kn = k0 + 64; if (kn >= K) kn -= K;
        int nx = cur + 2; if (nx >= 3) nx -= 3;
        const int nb = nx * 4096;
        load_lds16(gA0 + kn, lA0 + nb);
        load_lds16(gA1 + kn, lA1 + nb);
        load_lds16(gB0 + kn, lB0 + nb);
        load_lds16(gB1 + kn, lB1 + nb);

        const short* Ab = As + cur * 4096;
        const short* Bb = Bs + cur * 4096;

        short8 af[4], bfr[4];
        #pragma unroll
        for (int i = 0; i < 4; i++)
            af[i] = *(const short8*)&Ab[((wm + i * 16 + lm) * 4 + qs) * 8];
        #pragma unroll
        for (int j = 0; j < 4; j++)
            bfr[j] = *(const short8*)&Bb[((wn + j * 16 + lm) * 4 + qs) * 8];
        #pragma unroll
        for (int i = 0; i < 4; i++)
            #pragma unroll
            for (int j = 0; j < 4; j++)
                acc[i][j] = __builtin_amdgcn_mfma_f32_16x16x32_bf16(
                    af[i], bfr[j], acc[i][j], 0, 0, 0);

        cur = (cur + 1 == 3) ? 0 : cur + 1;
    }
    // drain outstanding (dummy) lds-DMA before this block's LDS can be
    // reassigned -- without this, late-landing writes corrupt another block.
    asm volatile("s_waitcnt vmcnt(0)" ::: "memory");

    const int r4 = (lane >> 4) << 2;     // C/D: row=(lane>>4)*4+reg, col=lane&15
    #pragma unroll
    for (int i = 0; i < 4; i++) {
        #pragma unroll
        for (int j = 0; j < 4; j++) {
            int colg = col0 + wn + j * 16 + lm;
            float bcol = bias[colg];
            #pragma unroll
            for (int r2 = 0; r2 < 4; r2++) {
                int rowg = row0 + wm + i * 16 + r4 + r2;
                size_t idx = (size_t)rowg * N + colg;
                float v = acc[i][j][r2] + bcol;
                if (mode == 0) {
                    if (colg >= 3072) v = 1.0f / (1.0f + expf(-v));
                    outb[idx] = f2bf(v);
                } else if (mode == 1) {
                    outf[idx] = v + res[idx];
                } else {
                    v = 0.5f * v * (1.0f + erff(v * 0.70710678118654752f));
                    outb[idx] = f2bf(v);
                }
            }
        }
    }
}

// ---------------------------------------------------------------------------
// Retention scan (chunk-parallel). qkvg bf16 [16384][4096]: q|k|v|g sections.
// channel c = b*1024 + h*64 + d  (4096 channels), chunks of 128 timesteps.
// ---------------------------------------------------------------------------
__global__ __launch_bounds__(256) void scan_pass1(
    const short* __restrict__ qkvg, const float* __restrict__ dlogit,
    float* __restrict__ carry)
{
    int j  = blockIdx.x >> 4;
    int c  = ((blockIdx.x & 15) << 8) + threadIdx.x;
    int b  = c >> 10;
    int col = c & 1023;
    float decay = 1.0f / (1.0f + expf(-dlogit[col >> 6]));
    size_t base = ((size_t)b * LSEQ + j * CHUNK) * 4096 + col;
    float s = 0.0f;
    for (int t = 0; t < CHUNK; ++t) {
        float kk = bf2f(qkvg[base + 1024]);
        float vv = bf2f(qkvg[base + 2048]);
        s = decay * s + kk * vv;
        base += 4096;
    }
    carry[j * 4096 + c] = s;
}

__global__ __launch_bounds__(256) void scan_combine(
    const float* __restrict__ carry, const float* __restrict__ dlogit,
    float* __restrict__ sinit)
{
    int c = blockIdx.x * 256 + threadIdx.x;
    float decay = 1.0f / (1.0f + expf(-dlogit[(c & 1023) >> 6]));
    float dp = powf(decay, (float)CHUNK);
    float s = 0.0f;
    for (int j = 0; j < NCH; ++j) {
        sinit[j * 4096 + c] = s;
        s = dp * s + carry[j * 4096 + c];
    }
}

__global__ __launch_bounds__(256) void scan_pass2(
    const short* __restrict__ qkvg, const float* __restrict__ dlogit,
    const float* __restrict__ sinit, short* __restrict__ att)
{
    int j  = blockIdx.x >> 4;
    int c  = ((blockIdx.x & 15) << 8) + threadIdx.x;
    int b  = c >> 10;
    int col = c & 1023;
    float decay = 1.0f / (1.0f + expf(-dlogit[col >> 6]));
    float s = sinit[j * 4096 + c];
    size_t base  = ((size_t)b * LSEQ + j * CHUNK) * 4096 + col;
    size_t obase = ((size_t)b * LSEQ + j * CHUNK) * 1024 + col;
    for (int t = 0; t < CHUNK; ++t) {
        float qq = bf2f(qkvg[base]);
        float kk = bf2f(qkvg[base + 1024]);
        float vv = bf2f(qkvg[base + 2048]);
        float gg = bf2f(qkvg[base + 3072]);
        s = decay * s + kk * vv;
        att[obase] = f2bf(gg * qq * s * 0.125f);   // scale = DH^-0.5
        base += 4096; obase += 1024;
    }
}

// ---------------------------------------------------------------------------
extern "C" void kernel_launch(void* const* d_in, const int* in_sizes, int n_in,
                              void* d_out, int out_size, void* d_ws, size_t ws_size,
                              hipStream_t stream)
{
    const float* x      = (const float*)d_in[0];
    const float* ln1_g  = (const float*)d_in[1];
    const float* ln1_b  = (const float*)d_in[2];
    const float* Wq     = (const float*)d_in[3];
    const float* bq     = (const float*)d_in[4];
    const float* Wk     = (const float*)d_in[5];
    const float* bk     = (const float*)d_in[6];
    const float* Wv     = (const float*)d_in[7];
    const float* bv     = (const float*)d_in[8];
    const float* Wg     = (const float*)d_in[9];
    const float* bg     = (const float*)d_in[10];
    const float* dlog   = (const float*)d_in[11];
    const float* Wo     = (const float*)d_in[12];
    const float* bo     = (const float*)d_in[13];
    const float* ln2_g  = (const float*)d_in[14];
    const float* ln2_b  = (const float*)d_in[15];
    const float* W1     = (const float*)d_in[16];
    const float* b1     = (const float*)d_in[17];
    const float* W2     = (const float*)d_in[18];
    const float* b2     = (const float*)d_in[19];
    float* out = (float*)d_out;

    char* ws = (char*)d_ws;
    size_t off = 0;
    auto alloc = [&](size_t bytes) -> void* {
        void* p = ws + off;
        off += (bytes + 255) & ~(size_t)255;
        return p;
    };
    // ---- workspace layout (~196 MB total) ----
    short* WqkvgT = (short*)alloc((size_t)4096 * 1024 * 2);   // 8 MB  [n=4096][k=1024]
    short* WoT    = (short*)alloc((size_t)1024 * 1024 * 2);   // 2 MB  [n=1024][k=1024]
    short* W1T    = (short*)alloc((size_t)4096 * 1024 * 2);   // 8 MB  [n=4096][k=1024]
    short* W2T    = (short*)alloc((size_t)1024 * 4096 * 2);   // 8 MB  [n=1024][k=4096]
    float* biasq  = (float*)alloc((size_t)4096 * 4);
    float* carry  = (float*)alloc((size_t)NCH * 4096 * 4);    // 0.5 MB
    float* sinit  = (float*)alloc((size_t)NCH * 4096 * 4);    // 0.5 MB
    short* bufA   = (short*)alloc((size_t)NROWS * 1024 * 2);  // 32 MB: y -> att -> h
    short* bufB   = (short*)alloc((size_t)NROWS * 4096 * 2);  // 128 MB: qkvg -> ff1
    // x2 lives in d_out (64 MB saved); final GEMM does in-place residual.
    float* x2 = out;
    short* ybuf = bufA;   // LN1 output
    short* att  = bufA;   // scan output (ybuf dead by then)
    short* hbuf = bufA;   // LN2 output (att dead by then)
    short* qkvg = bufB;
    short* ff1  = bufB;   // qkvg dead after scan_pass2
    (void)in_sizes; (void)n_in; (void)out_size;

    if (off > ws_size) return;  // ws too small: fail validation cleanly, not a segfault

    dim3 tb(32, 32);
    // weight prep: transpose + bf16 cast (must rerun every call; ws is poisoned)
    transpose_f32_bf16<<<dim3(32, 32), tb, 0, stream>>>(Wq, WqkvgT + 0 * 1024 * 1024, 1024, 1024);
    transpose_f32_bf16<<<dim3(32, 32), tb, 0, stream>>>(Wk, WqkvgT + 1 * 1024 * 1024, 1024, 1024);
    transpose_f32_bf16<<<dim3(32, 32), tb, 0, stream>>>(Wv, WqkvgT + 2 * 1024 * 1024, 1024, 1024);
    transpose_f32_bf16<<<dim3(32, 32), tb, 0, stream>>>(Wg, WqkvgT + 3 * 1024 * 1024, 1024, 1024);
    transpose_f32_bf16<<<dim3(32, 32), tb, 0, stream>>>(Wo, WoT, 1024, 1024);
    transpose_f32_bf16<<<dim3(128, 32), tb, 0, stream>>>(W1, W1T, 1024, 4096);
    transpose_f32_bf16<<<dim3(32, 128), tb, 0, stream>>>(W2, W2T, 4096, 1024);
    concat_bias<<<16, 256, 0, stream>>>(bq, bk, bv, bg, biasq);

    // LN1: x -> y(bf16)
    ln_kernel<<<NROWS, 256, 0, stream>>>(x, ln1_g, ln1_b, ybuf);

    // QKVG projection (fused bias + sigmoid on G)
    gemm_bf16<<<dim3(128, 32), 256, 0, stream>>>(
        ybuf, WqkvgT, biasq, nullptr, nullptr, qkvg, NROWS, 4096, 1024, 0);

    // retention scan
    scan_pass1 <<<NCH * 16, 256, 0, stream>>>(qkvg, dlog, carry);
    scan_combine<<<16, 256, 0, stream>>>(carry, dlog, sinit);
    scan_pass2 <<<NCH * 16, 256, 0, stream>>>(qkvg, dlog, sinit, att);

    // output projection + residual: x2 = x + att@Wo + bo   (x2 == d_out)
    gemm_bf16<<<dim3(128, 8), 256, 0, stream>>>(
        att, WoT, bo, x, x2, nullptr, NROWS, 1024, 1024, 1);

    // LN2: x2 -> h(bf16)
    ln_kernel<<<NROWS, 256, 0, stream>>>(x2, ln2_g, ln2_b, hbuf);

    // FFN: ff1 = gelu(h@W1 + b1)  (bf16)
    gemm_bf16<<<dim3(128, 32), 256, 0, stream>>>(
        hbuf, W1T, b1, nullptr, nullptr, ff1, NROWS, 4096, 1024, 2);

    // out = x2 + ff1@W2 + b2   (in-place residual on d_out)
    gemm_bf16<<<dim3(128, 8), 256, 0, stream>>>(
        ff1, W2T, b2, x2, out, nullptr, NROWS, 1024, 4096, 1);
}

// Round 8
// 916.299 us; speedup vs baseline: 1.2499x; 1.2094x over previous
//
#include <hip/hip_runtime.h>
#include <math.h>

// ---------------------------------------------------------------------------
// RetentionBlock: LN1 -> QKVG proj -> retention scan -> Wo + residual ->
//                 LN2 -> FFN(gelu) + residual
// B=4, L=4096, D_MODEL=1024, H=16, DH=64. All global inputs f32.
// R8: back to R4's measured-best GEMM K-loop (dist-1 LDS double-buffer,
//     __syncthreads, no dummy loads, no asm-waitcnt: R7 proved the 3-stage
//     vmcnt pipeline costs more VALU than it saves latency) + ONE new lever:
//     __launch_bounds__(256, 4) -> unified reg budget 128/wave
//     (was VGPR72+AGPR64=136 -> 3 blocks/CU). 4 blocks/CU, LDS 4x32=128<=160.
// ---------------------------------------------------------------------------

#define D_MODEL 1024
#define LSEQ    4096
#define BATCH   4
#define NROWS   (BATCH * LSEQ)      // 16384
#define HEADS   16
#define DH      64
#define CHUNK   128
#define NCH     (LSEQ / CHUNK)      // 32

typedef short  short8  __attribute__((ext_vector_type(8)));
typedef short  short4v __attribute__((ext_vector_type(4)));
typedef float  float4v __attribute__((ext_vector_type(4)));

__device__ inline short f2bf(float f) {
    unsigned u = __float_as_uint(f);
    u += 0x7fffu + ((u >> 16) & 1u);   // round-to-nearest-even
    return (short)(u >> 16);
}
__device__ inline float bf2f(short s) {
    return __uint_as_float(((unsigned)(unsigned short)s) << 16);
}

// async global->LDS, 16 bytes per lane; dest = wave-uniform base + lane*16
__device__ inline void load_lds16(const short* g, short* l) {
    __builtin_amdgcn_global_load_lds(
        (const __attribute__((address_space(1))) void*)g,
        (__attribute__((address_space(3))) void*)l,
        16, 0, 0);
}

// ---------------------------------------------------------------------------
// Transpose f32 [R][C] -> bf16 [C][R]
// ---------------------------------------------------------------------------
__global__ __launch_bounds__(1024) void transpose_f32_bf16(
    const float* __restrict__ in, short* __restrict__ out, int R, int C)
{
    __shared__ float tile[32][33];
    int tx = threadIdx.x, ty = threadIdx.y;
    int r = blockIdx.y * 32 + ty;
    int c = blockIdx.x * 32 + tx;
    tile[ty][tx] = in[(size_t)r * C + c];
    __syncthreads();
    out[(size_t)(blockIdx.x * 32 + ty) * R + blockIdx.y * 32 + tx] =
        f2bf(tile[tx][ty]);
}

// concat bq|bk|bv|bg -> bias_qkvg[4096]
__global__ __launch_bounds__(256) void concat_bias(
    const float* __restrict__ bq, const float* __restrict__ bk,
    const float* __restrict__ bv, const float* __restrict__ bg,
    float* __restrict__ out)
{
    int i = blockIdx.x * 256 + threadIdx.x;
    const float* src = (i < 1024) ? bq : (i < 2048) ? bk : (i < 3072) ? bv : bg;
    out[i] = src[i & 1023];
}

// ---------------------------------------------------------------------------
// Row LayerNorm: f32 [row][1024] -> bf16 [row][1024]. 1 block / row.
// ---------------------------------------------------------------------------
__global__ __launch_bounds__(256) void ln_kernel(
    const float* __restrict__ x, const float* __restrict__ g,
    const float* __restrict__ b, short* __restrict__ y)
{
    int row = blockIdx.x;
    int tid = threadIdx.x;
    const float4* xr = (const float4*)(x + (size_t)row * D_MODEL);
    float4 v = xr[tid];
    float s  = v.x + v.y + v.z + v.w;
    float ss = v.x * v.x + v.y * v.y + v.z * v.z + v.w * v.w;
    #pragma unroll
    for (int off = 32; off > 0; off >>= 1) {
        s  += __shfl_down(s, off);
        ss += __shfl_down(ss, off);
    }
    __shared__ float sbuf[8];
    int wv = tid >> 6, ln = tid & 63;
    if (ln == 0) { sbuf[wv] = s; sbuf[4 + wv] = ss; }
    __syncthreads();
    float tot  = sbuf[0] + sbuf[1] + sbuf[2] + sbuf[3];
    float tot2 = sbuf[4] + sbuf[5] + sbuf[6] + sbuf[7];
    float mu  = tot * (1.0f / D_MODEL);
    float var = tot2 * (1.0f / D_MODEL) - mu * mu;
    float rs  = rsqrtf(var + 1e-5f);
    float4 gg = ((const float4*)g)[tid];
    float4 bb = ((const float4*)b)[tid];
    short4v o;
    o.x = f2bf((v.x - mu) * rs * gg.x + bb.x);
    o.y = f2bf((v.y - mu) * rs * gg.y + bb.y);
    o.z = f2bf((v.z - mu) * rs * gg.z + bb.z);
    o.w = f2bf((v.w - mu) * rs * gg.w + bb.w);
    ((short4v*)y)[(size_t)row * 256 + tid] = o;
}

// ---------------------------------------------------------------------------
// bf16 MFMA GEMM: C[M][N] = A[M][K](bf16) * BT[N][K](bf16)^T, fused epilogue.
// Block 256 = 4 waves; tile 128x128; wave owns 64x64 as 4x4 of 16x16x32 MFMA.
// Staging: global_load_lds width=16, double-buffered LDS, 1 barrier/iter.
// LDS slot map (16B units): slot(row, q) = row*4 + (q ^ ((row>>1)&3)).
// Grid swizzle: windows of 8 x-blocks, y fastest (R4 measured-best).
// __launch_bounds__(256,4): cap unified regs at 128/wave -> 4 blocks/CU.
// mode 0: out_bf16 = (col>=3072 ? sigmoid : id)(acc + bias)        [QKVG]
// mode 1: out_f32  = acc + bias + res   (res==outf in-place is OK) [x2 / final]
// mode 2: out_bf16 = gelu_exact(acc + bias)                        [FFN mid]
// ---------------------------------------------------------------------------
__global__ __launch_bounds__(256, 4) void gemm_bf16(
    const short* __restrict__ A, const short* __restrict__ BT,
    const float* __restrict__ bias, const float* __restrict__ res,
    float* __restrict__ outf, short* __restrict__ outb,
    int M, int N, int K, int mode)
{
    __shared__ short As[2 * 4096];   // 2 x 8 KB, slot-swizzled
    __shared__ short Bs[2 * 4096];

    // ---- grid swizzle: window = 8 x-values * all y, y fastest inside ----
    const int gx = gridDim.x, gy = gridDim.y;
    const int lin = blockIdx.x + blockIdx.y * gx;
    const int win = 8 * gy;
    const int grp = lin / win;
    const int rem = lin - grp * win;
    const int bx = grp * 8 + (rem & 7);
    const int by = rem >> 3;

    const int tid  = threadIdx.x;
    const int row0 = bx * 128;
    const int col0 = by * 128;
    const int lane = tid & 63;
    const int wave = tid >> 6;
    const int wm = (wave & 1) << 6;
    const int wn = (wave >> 1) << 6;
    const int lm = lane & 15;            // m / n index within 16-tile
    const int q  = lane >> 4;            // kgroup 0..3 of this lane's fragment

    float4v acc[4][4];
    #pragma unroll
    for (int i = 0; i < 4; i++)
        #pragma unroll
        for (int j = 0; j < 4; j++)
            acc[i][j] = (float4v)(0.0f);

    // ---- staging decode (constant per lane; only k0 varies) ----
    const int s0 = wave * 64 + lane;
    const int s1 = 256 + wave * 64 + lane;
    const int r0 = s0 >> 2, q0 = (s0 & 3) ^ ((r0 >> 1) & 3);
    const int r1 = s1 >> 2, q1 = (s1 & 3) ^ ((r1 >> 1) & 3);
    const short* gA0 = A  + (size_t)(row0 + r0) * K + q0 * 8;
    const short* gA1 = A  + (size_t)(row0 + r1) * K + q1 * 8;
    const short* gB0 = BT + (size_t)(col0 + r0) * K + q0 * 8;
    const short* gB1 = BT + (size_t)(col0 + r1) * K + q1 * 8;
    short* lA0 = As + s0 * 8;
    short* lA1 = As + s1 * 8;
    short* lB0 = Bs + s0 * 8;
    short* lB1 = Bs + s1 * 8;

    // fragment-read swizzle: row = 16*t + lm  ->  (row>>1)&3 == (lm>>1)&3
    const int swz = (lm >> 1) & 3;
    const int qs  = q ^ swz;             // swizzled kgroup slot for reads

    // prologue: tile 0 -> buffer 0
    load_lds16(gA0, lA0);
    load_lds16(gA1, lA1);
    load_lds16(gB0, lB0);
    load_lds16(gB1, lB1);

    int p = 0;
    for (int k0 = 0; k0 < K; k0 += 32) {
        __syncthreads();                 // drains this tile's loads + prior reads
        const int kn = k0 + 32;
        const int po = p ^ 1;
        if (kn < K) {                    // prefetch next tile into other buffer
            load_lds16(gA0 + kn, lA0 + po * 4096);
            load_lds16(gA1 + kn, lA1 + po * 4096);
            load_lds16(gB0 + kn, lB0 + po * 4096);
            load_lds16(gB1 + kn, lB1 + po * 4096);
        }
        const short* Ab = As + p * 4096;
        const short* Bb = Bs + p * 4096;

        short8 af[4], bfr[4];
        #pragma unroll
        for (int i = 0; i < 4; i++)
            af[i] = *(const short8*)&Ab[((wm + i * 16 + lm) * 4 + qs) * 8];
        #pragma unroll
        for (int j = 0; j < 4; j++)
            bfr[j] = *(const short8*)&Bb[((wn + j * 16 + lm) * 4 + qs) * 8];
        #pragma unroll
        for (int i = 0; i < 4; i++)
            #pragma unroll
            for (int j = 0; j < 4; j++)
                acc[i][j] = __builtin_amdgcn_mfma_f32_16x16x32_bf16(
                    af[i], bfr[j], acc[i][j], 0, 0, 0);
        p ^= 1;
    }

    const int r4 = (lane >> 4) << 2;     // C/D: row=(lane>>4)*4+reg, col=lane&15
    #pragma unroll
    for (int i = 0; i < 4; i++) {
        #pragma unroll
        for (int j = 0; j < 4; j++) {
            int colg = col0 + wn + j * 16 + lm;
            float bcol = bias[colg];
            #pragma unroll
            for (int r2 = 0; r2 < 4; r2++) {
                int rowg = row0 + wm + i * 16 + r4 + r2;
                size_t idx = (size_t)rowg * N + colg;
                float v = acc[i][j][r2] + bcol;
                if (mode == 0) {
                    if (colg >= 3072) v = 1.0f / (1.0f + expf(-v));
                    outb[idx] = f2bf(v);
                } else if (mode == 1) {
                    outf[idx] = v + res[idx];
                } else {
                    v = 0.5f * v * (1.0f + erff(v * 0.70710678118654752f));
                    outb[idx] = f2bf(v);
                }
            }
        }
    }
}

// ---------------------------------------------------------------------------
// Retention scan (chunk-parallel). qkvg bf16 [16384][4096]: q|k|v|g sections.
// channel c = b*1024 + h*64 + d  (4096 channels), chunks of 128 timesteps.
// ---------------------------------------------------------------------------
__global__ __launch_bounds__(256) void scan_pass1(
    const short* __restrict__ qkvg, const float* __restrict__ dlogit,
    float* __restrict__ carry)
{
    int j  = blockIdx.x >> 4;
    int c  = ((blockIdx.x & 15) << 8) + threadIdx.x;
    int b  = c >> 10;
    int col = c & 1023;
    float decay = 1.0f / (1.0f + expf(-dlogit[col >> 6]));
    size_t base = ((size_t)b * LSEQ + j * CHUNK) * 4096 + col;
    float s = 0.0f;
    for (int t = 0; t < CHUNK; ++t) {
        float kk = bf2f(qkvg[base + 1024]);
        float vv = bf2f(qkvg[base + 2048]);
        s = decay * s + kk * vv;
        base += 4096;
    }
    carry[j * 4096 + c] = s;
}

__global__ __launch_bounds__(256) void scan_combine(
    const float* __restrict__ carry, const float* __restrict__ dlogit,
    float* __restrict__ sinit)
{
    int c = blockIdx.x * 256 + threadIdx.x;
    float decay = 1.0f / (1.0f + expf(-dlogit[(c & 1023) >> 6]));
    float dp = powf(decay, (float)CHUNK);
    float s = 0.0f;
    for (int j = 0; j < NCH; ++j) {
        sinit[j * 4096 + c] = s;
        s = dp * s + carry[j * 4096 + c];
    }
}

__global__ __launch_bounds__(256) void scan_pass2(
    const short* __restrict__ qkvg, const float* __restrict__ dlogit,
    const float* __restrict__ sinit, short* __restrict__ att)
{
    int j  = blockIdx.x >> 4;
    int c  = ((blockIdx.x & 15) << 8) + threadIdx.x;
    int b  = c >> 10;
    int col = c & 1023;
    float decay = 1.0f / (1.0f + expf(-dlogit[col >> 6]));
    float s = sinit[j * 4096 + c];
    size_t base  = ((size_t)b * LSEQ + j * CHUNK) * 4096 + col;
    size_t obase = ((size_t)b * LSEQ + j * CHUNK) * 1024 + col;
    for (int t = 0; t < CHUNK; ++t) {
        float qq = bf2f(qkvg[base]);
        float kk = bf2f(qkvg[base + 1024]);
        float vv = bf2f(qkvg[base + 2048]);
        float gg = bf2f(qkvg[base + 3072]);
        s = decay * s + kk * vv;
        att[obase] = f2bf(gg * qq * s * 0.125f);   // scale = DH^-0.5
        base += 4096; obase += 1024;
    }
}

// ---------------------------------------------------------------------------
extern "C" void kernel_launch(void* const* d_in, const int* in_sizes, int n_in,
                              void* d_out, int out_size, void* d_ws, size_t ws_size,
                              hipStream_t stream)
{
    const float* x      = (const float*)d_in[0];
    const float* ln1_g  = (const float*)d_in[1];
    const float* ln1_b  = (const float*)d_in[2];
    const float* Wq     = (const float*)d_in[3];
    const float* bq     = (const float*)d_in[4];
    const float* Wk     = (const float*)d_in[5];
    const float* bk     = (const float*)d_in[6];
    const float* Wv     = (const float*)d_in[7];
    const float* bv     = (const float*)d_in[8];
    const float* Wg     = (const float*)d_in[9];
    const float* bg     = (const float*)d_in[10];
    const float* dlog   = (const float*)d_in[11];
    const float* Wo     = (const float*)d_in[12];
    const float* bo     = (const float*)d_in[13];
    const float* ln2_g  = (const float*)d_in[14];
    const float* ln2_b  = (const float*)d_in[15];
    const float* W1     = (const float*)d_in[16];
    const float* b1     = (const float*)d_in[17];
    const float* W2     = (const float*)d_in[18];
    const float* b2     = (const float*)d_in[19];
    float* out = (float*)d_out;

    char* ws = (char*)d_ws;
    size_t off = 0;
    auto alloc = [&](size_t bytes) -> void* {
        void* p = ws + off;
        off += (bytes + 255) & ~(size_t)255;
        return p;
    };
    // ---- workspace layout (~196 MB total) ----
    short* WqkvgT = (short*)alloc((size_t)4096 * 1024 * 2);   // 8 MB  [n=4096][k=1024]
    short* WoT    = (short*)alloc((size_t)1024 * 1024 * 2);   // 2 MB  [n=1024][k=1024]
    short* W1T    = (short*)alloc((size_t)4096 * 1024 * 2);   // 8 MB  [n=4096][k=1024]
    short* W2T    = (short*)alloc((size_t)1024 * 4096 * 2);   // 8 MB  [n=1024][k=4096]
    float* biasq  = (float*)alloc((size_t)4096 * 4);
    float* carry  = (float*)alloc((size_t)NCH * 4096 * 4);    // 0.5 MB
    float* sinit  = (float*)alloc((size_t)NCH * 4096 * 4);    // 0.5 MB
    short* bufA   = (short*)alloc((size_t)NROWS * 1024 * 2);  // 32 MB: y -> att -> h
    short* bufB   = (short*)alloc((size_t)NROWS * 4096 * 2);  // 128 MB: qkvg -> ff1
    // x2 lives in d_out (64 MB saved); final GEMM does in-place residual.
    float* x2 = out;
    short* ybuf = bufA;   // LN1 output
    short* att  = bufA;   // scan output (ybuf dead by then)
    short* hbuf = bufA;   // LN2 output (att dead by then)
    short* qkvg = bufB;
    short* ff1  = bufB;   // qkvg dead after scan_pass2
    (void)in_sizes; (void)n_in; (void)out_size;

    if (off > ws_size) return;  // ws too small: fail validation cleanly, not a segfault

    dim3 tb(32, 32);
    // weight prep: transpose + bf16 cast (must rerun every call; ws is poisoned)
    transpose_f32_bf16<<<dim3(32, 32), tb, 0, stream>>>(Wq, WqkvgT + 0 * 1024 * 1024, 1024, 1024);
    transpose_f32_bf16<<<dim3(32, 32), tb, 0, stream>>>(Wk, WqkvgT + 1 * 1024 * 1024, 1024, 1024);
    transpose_f32_bf16<<<dim3(32, 32), tb, 0, stream>>>(Wv, WqkvgT + 2 * 1024 * 1024, 1024, 1024);
    transpose_f32_bf16<<<dim3(32, 32), tb, 0, stream>>>(Wg, WqkvgT + 3 * 1024 * 1024, 1024, 1024);
    transpose_f32_bf16<<<dim3(32, 32), tb, 0, stream>>>(Wo, WoT, 1024, 1024);
    transpose_f32_bf16<<<dim3(128, 32), tb, 0, stream>>>(W1, W1T, 1024, 4096);
    transpose_f32_bf16<<<dim3(32, 128), tb, 0, stream>>>(W2, W2T, 4096, 1024);
    concat_bias<<<16, 256, 0, stream>>>(bq, bk, bv, bg, biasq);

    // LN1: x -> y(bf16)
    ln_kernel<<<NROWS, 256, 0, stream>>>(x, ln1_g, ln1_b, ybuf);

    // QKVG projection (fused bias + sigmoid on G)
    gemm_bf16<<<dim3(128, 32), 256, 0, stream>>>(
        ybuf, WqkvgT, biasq, nullptr, nullptr, qkvg, NROWS, 4096, 1024, 0);

    // retention scan
    scan_pass1 <<<NCH * 16, 256, 0, stream>>>(qkvg, dlog, carry);
    scan_combine<<<16, 256, 0, stream>>>(carry, dlog, sinit);
    scan_pass2 <<<NCH * 16, 256, 0, stream>>>(qkvg, dlog, sinit, att);

    // output projection + residual: x2 = x + att@Wo + bo   (x2 == d_out)
    gemm_bf16<<<dim3(128, 8), 256, 0, stream>>>(
        att, WoT, bo, x, x2, nullptr, NROWS, 1024, 1024, 1);

    // LN2: x2 -> h(bf16)
    ln_kernel<<<NROWS, 256, 0, stream>>>(x2, ln2_g, ln2_b, hbuf);

    // FFN: ff1 = gelu(h@W1 + b1)  (bf16)
    gemm_bf16<<<dim3(128, 32), 256, 0, stream>>>(
        hbuf, W1T, b1, nullptr, nullptr, ff1, NROWS, 4096, 1024, 2);

    // out = x2 + ff1@W2 + b2   (in-place residual on d_out)
    gemm_bf16<<<dim3(128, 8), 256, 0, stream>>>(
        ff1, W2T, b2, x2, out, nullptr, NROWS, 1024, 4096, 1);
}